// Round 4
// baseline (243.731 us; speedup 1.0000x reference)
//
#include <hip/hip_runtime.h>
#include <stdint.h>

// SpatialHyperedgeMP: out = ((inc + head) @ cur) / rowsum(inc + head)
//   head_ij = (inc_ij > 0) / sqrt(cnt_i),  cnt_i = #positives in row i
//
// Kernels:
//   1) stats:  per-row fp64 sum + positive count -> invs[i]=1/sqrt(cnt), rdeg[i]=1/(s1+sqrt(cnt))
//   2) bprep:  cur fp32 -> bf16, transposed into MFMA-chunk layout in ws (nt=4 x kt=128 chunks)
//   3) gemm:   bf16 MFMA 16x16x32, BM=64 BN=128 BK=64, 512 thr (8 waves, wave tile 32x32),
//              2 blocks/CU (LDS 48.25KB), deep pipeline: raw s_barrier + counted vmcnt,
//              A-regs prefetched 2 tiles ahead, XOR-swizzled A LDS, setprio on MFMA.
//
// ws usage: 32KB invs + 32KB rdeg + 8MB B chunks.

#define NROWS 8192
#define DDIM  512

typedef float f32x4 __attribute__((ext_vector_type(4)));
typedef short s16x8 __attribute__((ext_vector_type(8)));

__device__ __forceinline__ unsigned short f2bf(float f) {
  union { float f; unsigned int u; } c; c.f = f;
  unsigned int u = c.u;
  unsigned int r = u + 0x7FFFu + ((u >> 16) & 1u);
  return (unsigned short)(r >> 16);
}

// ---------------- kernel 1: row stats ----------------
__global__ __launch_bounds__(256) void stats_kernel(const float* __restrict__ inc,
                                                    float* __restrict__ invs,
                                                    float* __restrict__ rdeg) {
  int row = blockIdx.x;
  int tid = threadIdx.x;
  const float4* p = (const float4*)(inc + (size_t)row * NROWS);
  double s = 0.0;
  int c = 0;
#pragma unroll
  for (int i = 0; i < 8; ++i) {
    float4 v = p[i * 256 + tid];
    s += (double)v.x + (double)v.y + (double)v.z + (double)v.w;
    c += (v.x > 0.f) + (v.y > 0.f) + (v.z > 0.f) + (v.w > 0.f);
  }
  for (int off = 32; off > 0; off >>= 1) {
    s += __shfl_down(s, off);
    c += __shfl_down(c, off);
  }
  __shared__ double sw[4];
  __shared__ int cw[4];
  int lane = tid & 63, wv = tid >> 6;
  if (lane == 0) { sw[wv] = s; cw[wv] = c; }
  __syncthreads();
  if (tid == 0) {
    double S = sw[0] + sw[1] + sw[2] + sw[3];
    int C = cw[0] + cw[1] + cw[2] + cw[3];
    double sq = sqrt((double)C);
    invs[row] = (C > 0) ? (float)(1.0 / sq) : 0.0f;
    rdeg[row] = (float)(1.0 / (S + sq));
  }
}

// ---------------- kernel 2: B prep (cur -> bf16 chunked-transposed) ----------------
// chunk layout: nt(4) x kt(128): 16KB chunk = [kg=8][nn=128][e=8] bf16
//   element (k, n): chunk(n>>7, k>>6), kg=(k&63)>>3, nn=n&127, e=k&7
__global__ __launch_bounds__(256) void bprep_kernel(const float* __restrict__ cur,
                                                    unsigned char* __restrict__ bws) {
  int idx = blockIdx.x * 256 + threadIdx.x;  // 0..524287
  int n = idx & 511;
  int kg9 = idx >> 9;  // 0..1023
  int kt = kg9 >> 3;
  int kg = kg9 & 7;
  int k0 = kt * 64 + kg * 8;
  union { unsigned short h[8]; uint4 q; } u;
#pragma unroll
  for (int e = 0; e < 8; ++e)
    u.h[e] = f2bf(cur[(size_t)(k0 + e) * DDIM + n]);
  int nt = n >> 7, nn = n & 127;
  size_t off = ((size_t)(nt * 128 + kt) << 14) + ((size_t)kg << 11) + ((size_t)nn << 4);
  *(uint4*)(bws + off) = u.q;
}

// ---------------- kernel 3: GEMM ----------------
// BM=64 BN=128 BK=64, 512 threads = 8 waves (2M x 4N), wave tile 32x32.
// LDS: B0,B1 = 16KB; A0,A1 = 8KB ([kg=8][slot=64][e=8] bf16, slot = row^kg); rdeg 256B.
// Total 48.25KB -> 2 blocks/CU -> 4 waves/SIMD: one block's barrier stall hides
// under the other block's compute.
// Pipeline invariant entering tile kt: per-wave vmem FIFO = [A(kt+1):2, B(kt+1):2].

#define FENCE() __builtin_amdgcn_sched_barrier(0)
#define BARRIER() __builtin_amdgcn_s_barrier()
#define WAITVM2() asm volatile("s_waitcnt vmcnt(2) lgkmcnt(0)" ::: "memory")
#define WAITVM0() asm volatile("s_waitcnt vmcnt(0) lgkmcnt(0)" ::: "memory")

__global__ __launch_bounds__(512, 4) void gemm_kernel(const float* __restrict__ inc,
                                                      const unsigned char* __restrict__ bws,
                                                      const float* __restrict__ invs,
                                                      const float* __restrict__ rdeg,
                                                      float* __restrict__ out) {
  __shared__ __align__(16) unsigned char smem[49664];
  unsigned char* const bBuf0 = smem;
  unsigned char* const bBuf1 = smem + 16384;
  unsigned char* const aBuf0 = smem + 32768;
  unsigned char* const aBuf1 = smem + 40960;
  float* const rdegS = (float*)(smem + 49152);

  const int tid = threadIdx.x;
  const int lane = tid & 63;
  const int wv = tid >> 6;
  const int nt = blockIdx.x;  // 0..3  (x fastest: the 4 A-partners run concurrently -> L3 dedup;
  const int mt = blockIdx.y;  // 0..127  each XCD serves one 2MB B-chunk -> B L2-resident)
  const int brow = mt * 64;
  const int bcol = nt * 128;
  const int wr = wv >> 2, wc = wv & 3;

  if (tid < 64) rdegS[tid] = rdeg[brow + tid];

  // A ownership: thread -> (row sm, k-octet sp); one b128 LDS write per tile.
  const int sm = tid >> 3;   // 0..63
  const int sp = tid & 7;    // 0..7
  const float4* gAr = (const float4*)(inc + (size_t)(brow + sm) * NROWS) + sp * 2;
  const float invr = invs[brow + sm];
  const int aWr = (sp << 10) + ((sm ^ sp) << 4);  // XOR swizzle (low 3 bits of row)

  const unsigned char* gB = bws + ((size_t)nt << 21);
  const int gOffLane = (wv << 10) + (lane << 4);
  const int ldsWave = (wv << 10);

  // fragment LDS byte offsets
  int aOff[2][2], bOff[2][2];
#pragma unroll
  for (int kh = 0; kh < 2; ++kh) {
    int kg = kh * 4 + (lane >> 4);
#pragma unroll
    for (int g = 0; g < 2; ++g) {
      int r = wr * 32 + g * 16 + (lane & 15);
      aOff[kh][g] = (kg << 10) + ((r ^ kg) << 4);  // matching read-side swizzle
      bOff[kh][g] = (kg << 11) + ((wc * 32 + g * 16 + (lane & 15)) << 4);
    }
  }

  f32x4 acc[2][2];
#pragma unroll
  for (int a = 0; a < 2; ++a)
#pragma unroll
    for (int b = 0; b < 2; ++b)
      acc[a][b] = (f32x4){0.f, 0.f, 0.f, 0.f};

  float4 x0, x1, y0, y1;

#define ISSUE_A(d0, d1, KT) do { d0 = gAr[(KT) * 16]; d1 = gAr[(KT) * 16 + 1]; } while (0)

#define ISSUE_B(KT, BDST) do {                                                            \
    const unsigned char* _g = gB + ((size_t)(KT) << 14);                                  \
    _Pragma("unroll")                                                                     \
    for (int _s = 0; _s < 2; ++_s)                                                        \
      __builtin_amdgcn_global_load_lds(                                                   \
          (const __attribute__((address_space(1))) unsigned int*)(_g + (_s << 13) + gOffLane), \
          (__attribute__((address_space(3))) unsigned int*)((BDST) + (_s << 13) + ldsWave),    \
          16, 0, 0);                                                                      \
  } while (0)

#define XFORM(s0, s1, ADST) do {                                                          \
    uint4 _w;                                                                             \
    _w.x = (unsigned int)f2bf(s0.x + (s0.x > 0.f ? invr : 0.f)) |                         \
           ((unsigned int)f2bf(s0.y + (s0.y > 0.f ? invr : 0.f)) << 16);                  \
    _w.y = (unsigned int)f2bf(s0.z + (s0.z > 0.f ? invr : 0.f)) |                         \
           ((unsigned int)f2bf(s0.w + (s0.w > 0.f ? invr : 0.f)) << 16);                  \
    _w.z = (unsigned int)f2bf(s1.x + (s1.x > 0.f ? invr : 0.f)) |                         \
           ((unsigned int)f2bf(s1.y + (s1.y > 0.f ? invr : 0.f)) << 16);                  \
    _w.w = (unsigned int)f2bf(s1.z + (s1.z > 0.f ? invr : 0.f)) |                         \
           ((unsigned int)f2bf(s1.w + (s1.w > 0.f ? invr : 0.f)) << 16);                  \
    *(uint4*)((ADST) + aWr) = _w;                                                         \
  } while (0)

#define MFMA_TILE(AC, BC) do {                                                            \
    __builtin_amdgcn_s_setprio(1);                                                        \
    _Pragma("unroll")                                                                     \
    for (int kh = 0; kh < 2; ++kh) {                                                      \
      s16x8 af[2], bfr[2];                                                                \
      _Pragma("unroll")                                                                   \
      for (int g = 0; g < 2; ++g) af[g] = *(const s16x8*)((AC) + aOff[kh][g]);            \
      _Pragma("unroll")                                                                   \
      for (int g = 0; g < 2; ++g) bfr[g] = *(const s16x8*)((BC) + bOff[kh][g]);           \
      _Pragma("unroll")                                                                   \
      for (int rg = 0; rg < 2; ++rg)                                                      \
        _Pragma("unroll")                                                                 \
        for (int cg = 0; cg < 2; ++cg)                                                    \
          acc[rg][cg] = __builtin_amdgcn_mfma_f32_16x16x32_bf16(af[rg], bfr[cg],          \
                                                                acc[rg][cg], 0, 0, 0);   \
    }                                                                                     \
    __builtin_amdgcn_s_setprio(0);                                                        \
  } while (0)

  // ---- prologue: queue -> [A(1):2, B(1):2] with buf0 ready ----
  ISSUE_A(x0, x1, 0);
  ISSUE_B(0, bBuf0);
  ISSUE_A(y0, y1, 1);
  XFORM(x0, x1, aBuf0);  // compiler auto-waits A(0) regs precisely
  FENCE();
  WAITVM2();             // retire B(0); leave A(1) in flight
  FENCE();
  BARRIER();
  FENCE();
  ISSUE_B(1, bBuf1);

  // ---- steady: tiles 0..125, unrolled by 2 for static reg/buffer names ----
  for (int kt = 0; kt < 126; kt += 2) {
    // even tile kt: compute(a0,b0); pending y=A(kt+1)
    ISSUE_A(x0, x1, kt + 2);
    MFMA_TILE(aBuf0, bBuf0);
    XFORM(y0, y1, aBuf1);
    FENCE();
    WAITVM2();           // retire B(kt+1); leave A(kt+2)
    FENCE();
    BARRIER();
    FENCE();
    ISSUE_B(kt + 2, bBuf0);
    // odd tile kt+1: compute(a1,b1); pending x=A(kt+2)
    ISSUE_A(y0, y1, kt + 3);
    MFMA_TILE(aBuf1, bBuf1);
    XFORM(x0, x1, aBuf0);
    FENCE();
    WAITVM2();           // retire B(kt+2); leave A(kt+3)
    FENCE();
    BARRIER();
    FENCE();
    ISSUE_B(kt + 3, bBuf1);
  }

  // ---- tail: tile 126 ----
  MFMA_TILE(aBuf0, bBuf0);
  XFORM(y0, y1, aBuf1);  // A(127)
  FENCE();
  WAITVM0();             // drain B(127); nothing else outstanding
  FENCE();
  BARRIER();
  FENCE();
  // ---- tail: tile 127 ----
  MFMA_TILE(aBuf1, bBuf1);

  // ---- epilogue: * rdeg, store fp32 ----
#pragma unroll
  for (int rg = 0; rg < 2; ++rg) {
    int rb = wr * 32 + rg * 16 + ((lane >> 4) << 2);
#pragma unroll
    for (int cg = 0; cg < 2; ++cg) {
      int col = bcol + wc * 32 + cg * 16 + (lane & 15);
#pragma unroll
      for (int r = 0; r < 4; ++r) {
        int rl = rb + r;
        out[(size_t)(brow + rl) * DDIM + col] = acc[rg][cg][r] * rdegS[rl];
      }
    }
  }
#undef ISSUE_A
#undef ISSUE_B
#undef XFORM
#undef MFMA_TILE
}

extern "C" void kernel_launch(void* const* d_in, const int* in_sizes, int n_in,
                              void* d_out, int out_size, void* d_ws, size_t ws_size,
                              hipStream_t stream) {
  const float* cur = (const float*)d_in[0];          // [8192, 512] fp32
  const float* incm = (const float*)d_in[1];         // [8192, 8192] fp32
  float* out = (float*)d_out;                        // [8192, 512] fp32
  unsigned char* ws = (unsigned char*)d_ws;
  float* invs = (float*)ws;                          // 32KB
  float* rdeg = (float*)(ws + 32768);                // 32KB
  unsigned char* bws = ws + 65536;                   // 8MB B chunks

  hipLaunchKernelGGL(stats_kernel, dim3(NROWS), dim3(256), 0, stream, incm, invs, rdeg);
  hipLaunchKernelGGL(bprep_kernel, dim3((NROWS * DDIM / 8) / 256), dim3(256), 0, stream,
                     cur, bws);
  hipLaunchKernelGGL(gemm_kernel, dim3(4, 128), dim3(512), 0, stream, incm, bws, invs, rdeg, out);
}

// Round 5
// 207.191 us; speedup vs baseline: 1.1764x; 1.1764x over previous
//
#include <hip/hip_runtime.h>
#include <stdint.h>

// SpatialHyperedgeMP: out = ((inc + head) @ cur) / rowsum(inc + head)
//   head_ij = (inc_ij > 0) / sqrt(cnt_i),  cnt_i = #positives in row i
// Decomposition (single fused pass over inc):
//   out[i] = (inc@cur + invs_i * (mask@cur)) * rdeg_i
//   invs_i = 1/sqrt(cnt_i),  rdeg_i = 1/(s1_i + sqrt(cnt_i))
//   s1 (fp64) and cnt (int) accumulated during A staging -> exact denominator.
//
// Kernels:
//   1) bprep: cur fp32 -> bf16, transposed into MFMA-chunk layout in ws (nt=2)
//   2) gemm:  dual bf16 MFMA 16x16x32 (inc and mask operands), BM=32 BN=256 BK=64,
//             512 thr (8 waves, 1M x 8N, wave tile 32x32), 2 blocks/CU (LDS 72.3KB),
//             counted-vmcnt pipeline, XOR-swizzled A LDS, mask fragment derived
//             in-register from the A1 fragment (no extra LDS/HBM).
//
// ws usage: 8MB B chunks only.

#define NROWS 8192
#define DDIM  512

typedef float f32x4 __attribute__((ext_vector_type(4)));
typedef short s16x8 __attribute__((ext_vector_type(8)));
typedef unsigned int u32x4 __attribute__((ext_vector_type(4)));

__device__ __forceinline__ unsigned short f2bf(float f) {
  union { float f; unsigned int u; } c; c.f = f;
  unsigned int u = c.u;
  unsigned int r = u + 0x7FFFu + ((u >> 16) & 1u);
  return (unsigned short)(r >> 16);
}

// bf16-pair positive test: per 16-bit half, 0x3F80 (bf16 1.0) if value > 0 else 0.
__device__ __forceinline__ s16x8 pos_mask_frag(s16x8 a) {
  union { s16x8 s; u32x4 u; } in, out;
  in.s = a;
#pragma unroll
  for (int i = 0; i < 4; ++i) {
    unsigned int v = in.u[i];
    unsigned int nz = ((v & 0x7FFF7FFFu) + 0x7FFF7FFFu) & 0x80008000u;  // halfwise mag!=0
    unsigned int pos = nz & ~v;                                          // ...and sign==0
    out.u[i] = (pos >> 15) * 0x3F80u;  // bit0/bit16 -> 0x3F80 per half (u24 mul safe)
  }
  return out.s;
}

// ---------------- kernel 1: B prep (cur -> bf16 chunked-transposed) ----------------
// chunk layout: nt(2) x kt(128): 32KB chunk = [kg=8][nn=256][e=8] bf16
__global__ __launch_bounds__(256) void bprep_kernel(const float* __restrict__ cur,
                                                    unsigned char* __restrict__ bws) {
  int idx = blockIdx.x * 256 + threadIdx.x;  // 0..524287
  int n = idx & 511;
  int kg9 = idx >> 9;  // 0..1023
  int kt = kg9 >> 3;
  int kg = kg9 & 7;
  int k0 = kt * 64 + kg * 8;
  union { unsigned short h[8]; uint4 q; } u;
#pragma unroll
  for (int e = 0; e < 8; ++e)
    u.h[e] = f2bf(cur[(size_t)(k0 + e) * DDIM + n]);
  int nt = n >> 8, nn = n & 255;
  size_t off = ((size_t)(nt * 128 + kt) << 15) + ((size_t)kg << 12) + ((size_t)nn << 4);
  *(uint4*)(bws + off) = u.q;
}

// ---------------- kernel 2: fused stats + dual-GEMM ----------------
// BM=32 BN=256 BK=64, 512 threads = 8 waves (1M x 8N), wave tile 32x32.
// LDS: B0,B1 = 32KB; A0,A1 = 4KB ([kg=8][slot=32][e=8] bf16, slot = row^kg); stats 256B.
// Total 72.5KB -> 2 blocks/CU. Partners (nt=0,1 of same mt) are dispatch-adjacent
// -> same CU -> A deduped in L1/L2 (R3 evidence: FETCH ~= A read once).
// Pipeline invariant entering tile kt: per-wave vmem FIFO = [A(kt+1):1, B(kt+1):4].

#define FENCE() __builtin_amdgcn_sched_barrier(0)
#define BARRIER() __builtin_amdgcn_s_barrier()
#define WAITVM1() asm volatile("s_waitcnt vmcnt(1) lgkmcnt(0)" ::: "memory")
#define WAITVM0() asm volatile("s_waitcnt vmcnt(0) lgkmcnt(0)" ::: "memory")

__global__ __launch_bounds__(512, 4) void gemm_kernel(const float* __restrict__ inc,
                                                      const unsigned char* __restrict__ bws,
                                                      float* __restrict__ out) {
  __shared__ __align__(16) unsigned char smem[74240];
  unsigned char* const bBuf0 = smem;
  unsigned char* const bBuf1 = smem + 32768;
  unsigned char* const aBuf0 = smem + 65536;
  unsigned char* const aBuf1 = smem + 69632;
  float* const invsS = (float*)(smem + 73728);   // 32 floats
  float* const rdegS = invsS + 32;               // 32 floats

  const int tid = threadIdx.x;
  const int lane = tid & 63;
  const int wv = tid >> 6;
  const int nt = blockIdx.x;  // 0..1
  const int mt = blockIdx.y;  // 0..255
  const int brow = mt * 32;
  const int bcol = nt * 256;

  // A ownership: thread -> (row sm, float4-slot sp); one b64 LDS write per tile.
  const int sm = tid >> 4;   // 0..31
  const int sp = tid & 15;   // 0..15  (k = sp*4 .. sp*4+3)
  const int kgw = sp >> 1, half = sp & 1;
  const float4* gAr = (const float4*)(inc + (size_t)(brow + sm) * NROWS) + sp;
  const int aWr = (kgw << 9) + (((sm ^ kgw)) << 4) + (half << 3);

  const unsigned char* gB = bws + ((size_t)(nt * 128) << 15);
  const int gOffLane = (wv << 10) + (lane << 4);
  const int ldsWave = (wv << 10);

  // fragment LDS byte offsets: A rows wr*16+(lane&15), B cols wv*32+cg*16+(lane&15)
  int aOff[2][2], bOff[2][2];
#pragma unroll
  for (int kh = 0; kh < 2; ++kh) {
    int kg = kh * 4 + (lane >> 4);
#pragma unroll
    for (int g = 0; g < 2; ++g) {
      int r = g * 16 + (lane & 15);
      aOff[kh][g] = (kg << 9) + ((r ^ kg) << 4);
      bOff[kh][g] = (kg << 12) + ((wv * 32 + g * 16 + (lane & 15)) << 4);
    }
  }

  f32x4 acc1[2][2], acc2[2][2];
#pragma unroll
  for (int a = 0; a < 2; ++a)
#pragma unroll
    for (int b = 0; b < 2; ++b) {
      acc1[a][b] = (f32x4){0.f, 0.f, 0.f, 0.f};
      acc2[a][b] = (f32x4){0.f, 0.f, 0.f, 0.f};
    }

  double s1d = 0.0;
  int cnt = 0;
  float4 x, y;

#define ISSUE_A(d, KT) do { d = gAr[(KT) * 16]; } while (0)

#define ISSUE_B(KT, BDST) do {                                                            \
    const unsigned char* _g = gB + ((size_t)(KT) << 15);                                  \
    _Pragma("unroll")                                                                     \
    for (int _s = 0; _s < 4; ++_s)                                                        \
      __builtin_amdgcn_global_load_lds(                                                   \
          (const __attribute__((address_space(1))) unsigned int*)(_g + (_s << 13) + gOffLane), \
          (__attribute__((address_space(3))) unsigned int*)((BDST) + (_s << 13) + ldsWave),    \
          16, 0, 0);                                                                      \
  } while (0)

// stage A tile: accumulate exact stats, convert to bf16, LDS write (swizzled)
#define XFORM(s0, ADST) do {                                                              \
    s1d += (double)s0.x + (double)s0.y + (double)s0.z + (double)s0.w;                     \
    cnt += (s0.x > 0.f) + (s0.y > 0.f) + (s0.z > 0.f) + (s0.w > 0.f);                     \
    unsigned long long pk =                                                               \
        (unsigned long long)f2bf(s0.x) |                                                  \
        ((unsigned long long)f2bf(s0.y) << 16) |                                          \
        ((unsigned long long)f2bf(s0.z) << 32) |                                          \
        ((unsigned long long)f2bf(s0.w) << 48);                                           \
    *(unsigned long long*)((ADST) + aWr) = pk;                                            \
  } while (0)

#define MFMA_TILE(AC, BC) do {                                                            \
    __builtin_amdgcn_s_setprio(1);                                                        \
    _Pragma("unroll")                                                                     \
    for (int kh = 0; kh < 2; ++kh) {                                                      \
      s16x8 af[2], am[2], bfr[2];                                                         \
      _Pragma("unroll")                                                                   \
      for (int g = 0; g < 2; ++g) af[g] = *(const s16x8*)((AC) + aOff[kh][g]);            \
      _Pragma("unroll")                                                                   \
      for (int g = 0; g < 2; ++g) bfr[g] = *(const s16x8*)((BC) + bOff[kh][g]);           \
      _Pragma("unroll")                                                                   \
      for (int g = 0; g < 2; ++g) am[g] = pos_mask_frag(af[g]);                           \
      _Pragma("unroll")                                                                   \
      for (int rg = 0; rg < 2; ++rg)                                                      \
        _Pragma("unroll")                                                                 \
        for (int cg = 0; cg < 2; ++cg) {                                                  \
          acc1[rg][cg] = __builtin_amdgcn_mfma_f32_16x16x32_bf16(af[rg], bfr[cg],         \
                                                                 acc1[rg][cg], 0, 0, 0); \
          acc2[rg][cg] = __builtin_amdgcn_mfma_f32_16x16x32_bf16(am[rg], bfr[cg],         \
                                                                 acc2[rg][cg], 0, 0, 0); \
        }                                                                                 \
    }                                                                                     \
    __builtin_amdgcn_s_setprio(0);                                                        \
  } while (0)

  // ---- prologue: queue -> [A(1):1, B(1):4] with buf0 ready ----
  ISSUE_A(x, 0);
  ISSUE_B(0, bBuf0);
  ISSUE_A(y, 1);
  XFORM(x, aBuf0);       // compiler auto-waits A(0) regs precisely
  FENCE();
  WAITVM1();             // retire B(0); leave A(1) in flight
  FENCE();
  BARRIER();
  FENCE();
  ISSUE_B(1, bBuf1);

  // ---- steady: tiles 0..125, unrolled by 2 for static reg/buffer names ----
  for (int kt = 0; kt < 126; kt += 2) {
    // even tile kt: compute(a0,b0); pending y=A(kt+1)
    ISSUE_A(x, kt + 2);
    MFMA_TILE(aBuf0, bBuf0);
    XFORM(y, aBuf1);
    FENCE();
    WAITVM1();           // retire B(kt+1); leave A(kt+2)
    FENCE();
    BARRIER();
    FENCE();
    ISSUE_B(kt + 2, bBuf0);
    // odd tile kt+1: compute(a1,b1); pending x=A(kt+2)
    ISSUE_A(y, kt + 3);
    MFMA_TILE(aBuf1, bBuf1);
    XFORM(x, aBuf0);
    FENCE();
    WAITVM1();           // retire B(kt+2); leave A(kt+3)
    FENCE();
    BARRIER();
    FENCE();
    ISSUE_B(kt + 3, bBuf1);
  }

  // ---- tail: tile 126 ----
  MFMA_TILE(aBuf0, bBuf0);
  XFORM(y, aBuf1);       // A(127)
  FENCE();
  WAITVM0();             // drain B(127); nothing else outstanding
  FENCE();
  BARRIER();
  FENCE();
  // ---- tail: tile 127 ----
  MFMA_TILE(aBuf1, bBuf1);

  // ---- stats reduction: 16 lanes per row (consecutive lanes in wave) ----
#pragma unroll
  for (int o = 1; o < 16; o <<= 1) {
    s1d += __shfl_xor(s1d, o);
    cnt += __shfl_xor(cnt, o);
  }
  if (sp == 0) {
    double sq = sqrt((double)cnt);
    invsS[sm] = (cnt > 0) ? (float)(1.0 / sq) : 0.0f;
    rdegS[sm] = (float)(1.0 / (s1d + sq));
  }
  __syncthreads();

  // ---- epilogue: (acc1 + invs*acc2) * rdeg, store fp32 ----
#pragma unroll
  for (int rg = 0; rg < 2; ++rg) {
    int rb = rg * 16 + ((lane >> 4) << 2);
#pragma unroll
    for (int cg = 0; cg < 2; ++cg) {
      int col = bcol + wv * 32 + cg * 16 + (lane & 15);
#pragma unroll
      for (int r = 0; r < 4; ++r) {
        int rl = rb + r;
        out[(size_t)(brow + rl) * DDIM + col] =
            (acc1[rg][cg][r] + invsS[rl] * acc2[rg][cg][r]) * rdegS[rl];
      }
    }
  }
#undef ISSUE_A
#undef ISSUE_B
#undef XFORM
#undef MFMA_TILE
}

extern "C" void kernel_launch(void* const* d_in, const int* in_sizes, int n_in,
                              void* d_out, int out_size, void* d_ws, size_t ws_size,
                              hipStream_t stream) {
  const float* cur = (const float*)d_in[0];          // [8192, 512] fp32
  const float* incm = (const float*)d_in[1];         // [8192, 8192] fp32
  float* out = (float*)d_out;                        // [8192, 512] fp32
  unsigned char* bws = (unsigned char*)d_ws;         // 8MB B chunks

  hipLaunchKernelGGL(bprep_kernel, dim3((NROWS * DDIM / 8) / 256), dim3(256), 0, stream,
                     cur, bws);
  hipLaunchKernelGGL(gemm_kernel, dim3(2, 256), dim3(512), 0, stream, incm, bws, out);
}

// Round 6
// 182.664 us; speedup vs baseline: 1.3343x; 1.1343x over previous
//
#include <hip/hip_runtime.h>
#include <stdint.h>

// SpatialHyperedgeMP: out = ((inc + head) @ cur) / rowsum(inc + head)
//   head_ij = (inc_ij > 0) / sqrt(cnt_i),  cnt_i = #positives in row i
// Decomposition (single fused pass over inc):
//   out[i] = (inc@cur + invs_i * (mask@cur)) * rdeg_i
//   invs_i = 1/sqrt(cnt_i),  rdeg_i = 1/(s1_i + sqrt(cnt_i))
//   s1 (fp64) and cnt (int) accumulated during A staging -> exact denominator.
//
// R6: VALU diet. Mask operand staged in LDS (computed once per element during
// XFORM, not per-MFMA-fragment); bf16 conversion via v_cvt_pk_bf16_f32 (RNE).
// LDS = 81920 B/block exactly -> still 2 blocks/CU; epilogue stats reuse bBuf0.
//
// ws usage: 8MB B chunks only.

#define NROWS 8192
#define DDIM  512

typedef float f32x4 __attribute__((ext_vector_type(4)));
typedef short s16x8 __attribute__((ext_vector_type(8)));

__device__ __forceinline__ unsigned short f2bf(float f) {
  union { float f; unsigned int u; } c; c.f = f;
  unsigned int u = c.u;
  unsigned int r = u + 0x7FFFu + ((u >> 16) & 1u);
  return (unsigned short)(r >> 16);
}

// ---------------- kernel 1: B prep (cur -> bf16 chunked-transposed) ----------------
// chunk layout: nt(2) x kt(128): 32KB chunk = [kg=8][nn=256][e=8] bf16
__global__ __launch_bounds__(256) void bprep_kernel(const float* __restrict__ cur,
                                                    unsigned char* __restrict__ bws) {
  int idx = blockIdx.x * 256 + threadIdx.x;  // 0..524287
  int n = idx & 511;
  int kg9 = idx >> 9;  // 0..1023
  int kt = kg9 >> 3;
  int kg = kg9 & 7;
  int k0 = kt * 64 + kg * 8;
  union { unsigned short h[8]; uint4 q; } u;
#pragma unroll
  for (int e = 0; e < 8; ++e)
    u.h[e] = f2bf(cur[(size_t)(k0 + e) * DDIM + n]);
  int nt = n >> 8, nn = n & 255;
  size_t off = ((size_t)(nt * 128 + kt) << 15) + ((size_t)kg << 12) + ((size_t)nn << 4);
  *(uint4*)(bws + off) = u.q;
}

// ---------------- kernel 2: fused stats + dual-GEMM ----------------
// BM=32 BN=256 BK=64, 512 threads = 8 waves (1M x 8N), wave tile 32x32.
// LDS (81920 B): B0,B1 = 32KB; A0,A1 = 4KB; M0,M1 = 4KB
//   A/M layout [kg=8][slot=32][e=8] bf16, slot = row^kg (conflict-free b64 write / b128 read).
// Stats (invs/rdeg, 256B) reuse bBuf0 after the K-loop (B buffers dead by then).
// Pipeline invariant entering tile kt: per-wave vmem FIFO = [A(kt+1):1, B(kt+1):4].

#define FENCE() __builtin_amdgcn_sched_barrier(0)
#define BARRIER() __builtin_amdgcn_s_barrier()
#define WAITVM1() asm volatile("s_waitcnt vmcnt(1) lgkmcnt(0)" ::: "memory")
#define WAITVM0() asm volatile("s_waitcnt vmcnt(0) lgkmcnt(0)" ::: "memory")

__global__ __launch_bounds__(512, 4) void gemm_kernel(const float* __restrict__ inc,
                                                      const unsigned char* __restrict__ bws,
                                                      float* __restrict__ out) {
  __shared__ __align__(16) unsigned char smem[81920];
  unsigned char* const bBuf0 = smem;
  unsigned char* const bBuf1 = smem + 32768;
  unsigned char* const aBuf0 = smem + 65536;
  unsigned char* const aBuf1 = smem + 69632;
  unsigned char* const mBuf0 = smem + 73728;
  unsigned char* const mBuf1 = smem + 77824;

  const int tid = threadIdx.x;
  const int lane = tid & 63;
  const int wv = tid >> 6;
  const int nt = blockIdx.x;  // 0..1
  const int mt = blockIdx.y;  // 0..255
  const int brow = mt * 32;
  const int bcol = nt * 256;

  // A ownership: thread -> (row sm, float4-slot sp); one b64 LDS write (x2: A,M) per tile.
  const int sm = tid >> 4;   // 0..31
  const int sp = tid & 15;   // 0..15  (k = sp*4 .. sp*4+3)
  const int kgw = sp >> 1, half = sp & 1;
  const float4* gAr = (const float4*)(inc + (size_t)(brow + sm) * NROWS) + sp;
  const int aWr = (kgw << 9) + (((sm ^ kgw)) << 4) + (half << 3);

  const unsigned char* gB = bws + ((size_t)(nt * 128) << 15);
  const int gOffLane = (wv << 10) + (lane << 4);
  const int ldsWave = (wv << 10);

  // fragment LDS byte offsets: A/M rows g*16+(lane&15), B cols wv*32+cg*16+(lane&15)
  int aOff[2][2], bOff[2][2];
#pragma unroll
  for (int kh = 0; kh < 2; ++kh) {
    int kg = kh * 4 + (lane >> 4);
#pragma unroll
    for (int g = 0; g < 2; ++g) {
      int r = g * 16 + (lane & 15);
      aOff[kh][g] = (kg << 9) + ((r ^ kg) << 4);
      bOff[kh][g] = (kg << 12) + ((wv * 32 + g * 16 + (lane & 15)) << 4);
    }
  }

  f32x4 acc1[2][2], acc2[2][2];
#pragma unroll
  for (int a = 0; a < 2; ++a)
#pragma unroll
    for (int b = 0; b < 2; ++b) {
      acc1[a][b] = (f32x4){0.f, 0.f, 0.f, 0.f};
      acc2[a][b] = (f32x4){0.f, 0.f, 0.f, 0.f};
    }

  double s1d = 0.0;
  int cnt = 0;
  float4 x, y;

#define ISSUE_A(d, KT) do { d = gAr[(KT) * 16]; } while (0)

#define ISSUE_B(KT, BDST) do {                                                            \
    const unsigned char* _g = gB + ((size_t)(KT) << 15);                                  \
    _Pragma("unroll")                                                                     \
    for (int _s = 0; _s < 4; ++_s)                                                        \
      __builtin_amdgcn_global_load_lds(                                                   \
          (const __attribute__((address_space(1))) unsigned int*)(_g + (_s << 13) + gOffLane), \
          (__attribute__((address_space(3))) unsigned int*)((BDST) + (_s << 13) + ldsWave),    \
          16, 0, 0);                                                                      \
  } while (0)

// stage A tile: exact stats, RNE bf16 via v_cvt_pk, mask bf16 (1.0/0.0) -> LDS.
// Compares are shared (CSE) between cnt and the mask selects.
#define XFORM(s0, ADST, MDST) do {                                                        \
    s1d += (double)s0.x + (double)s0.y + (double)s0.z + (double)s0.w;                     \
    cnt += (s0.x > 0.f) + (s0.y > 0.f) + (s0.z > 0.f) + (s0.w > 0.f);                     \
    unsigned dlo, dhi;                                                                    \
    asm("v_cvt_pk_bf16_f32 %0, %1, %2" : "=v"(dlo) : "v"(s0.x), "v"(s0.y));               \
    asm("v_cvt_pk_bf16_f32 %0, %1, %2" : "=v"(dhi) : "v"(s0.z), "v"(s0.w));               \
    unsigned mlo = (s0.x > 0.f ? 0x3F80u : 0u) | (s0.y > 0.f ? 0x3F800000u : 0u);         \
    unsigned mhi = (s0.z > 0.f ? 0x3F80u : 0u) | (s0.w > 0.f ? 0x3F800000u : 0u);         \
    *(unsigned long long*)((ADST) + aWr) =                                                \
        (unsigned long long)dlo | ((unsigned long long)dhi << 32);                        \
    *(unsigned long long*)((MDST) + aWr) =                                                \
        (unsigned long long)mlo | ((unsigned long long)mhi << 32);                        \
  } while (0)

#define MFMA_TILE(AC, MC, BC) do {                                                        \
    __builtin_amdgcn_s_setprio(1);                                                        \
    _Pragma("unroll")                                                                     \
    for (int kh = 0; kh < 2; ++kh) {                                                      \
      s16x8 af[2], am[2], bfr[2];                                                         \
      _Pragma("unroll")                                                                   \
      for (int g = 0; g < 2; ++g) af[g] = *(const s16x8*)((AC) + aOff[kh][g]);            \
      _Pragma("unroll")                                                                   \
      for (int g = 0; g < 2; ++g) am[g] = *(const s16x8*)((MC) + aOff[kh][g]);            \
      _Pragma("unroll")                                                                   \
      for (int g = 0; g < 2; ++g) bfr[g] = *(const s16x8*)((BC) + bOff[kh][g]);           \
      _Pragma("unroll")                                                                   \
      for (int rg = 0; rg < 2; ++rg)                                                      \
        _Pragma("unroll")                                                                 \
        for (int cg = 0; cg < 2; ++cg) {                                                  \
          acc1[rg][cg] = __builtin_amdgcn_mfma_f32_16x16x32_bf16(af[rg], bfr[cg],         \
                                                                 acc1[rg][cg], 0, 0, 0); \
          acc2[rg][cg] = __builtin_amdgcn_mfma_f32_16x16x32_bf16(am[rg], bfr[cg],         \
                                                                 acc2[rg][cg], 0, 0, 0); \
        }                                                                                 \
    }                                                                                     \
    __builtin_amdgcn_s_setprio(0);                                                        \
  } while (0)

  // ---- prologue: queue -> [A(1):1, B(1):4] with buf0 ready ----
  ISSUE_A(x, 0);
  ISSUE_B(0, bBuf0);
  ISSUE_A(y, 1);
  XFORM(x, aBuf0, mBuf0);  // compiler auto-waits A(0) regs precisely
  FENCE();
  WAITVM1();               // retire B(0); leave A(1) in flight
  FENCE();
  BARRIER();
  FENCE();
  ISSUE_B(1, bBuf1);

  // ---- steady: tiles 0..125, unrolled by 2 for static reg/buffer names ----
  for (int kt = 0; kt < 126; kt += 2) {
    // even tile kt: compute(buf0); pending y=A(kt+1)
    ISSUE_A(x, kt + 2);
    MFMA_TILE(aBuf0, mBuf0, bBuf0);
    XFORM(y, aBuf1, mBuf1);
    FENCE();
    WAITVM1();           // retire B(kt+1); leave A(kt+2)
    FENCE();
    BARRIER();
    FENCE();
    ISSUE_B(kt + 2, bBuf0);
    // odd tile kt+1: compute(buf1); pending x=A(kt+2)
    ISSUE_A(y, kt + 3);
    MFMA_TILE(aBuf1, mBuf1, bBuf1);
    XFORM(x, aBuf0, mBuf0);
    FENCE();
    WAITVM1();           // retire B(kt+2); leave A(kt+3)
    FENCE();
    BARRIER();
    FENCE();
    ISSUE_B(kt + 3, bBuf1);
  }

  // ---- tail: tile 126 ----
  MFMA_TILE(aBuf0, mBuf0, bBuf0);
  XFORM(y, aBuf1, mBuf1);  // A(127)
  FENCE();
  WAITVM0();               // drain B(127); nothing else outstanding
  FENCE();
  BARRIER();
  FENCE();
  // ---- tail: tile 127 ----
  MFMA_TILE(aBuf1, mBuf1, bBuf1);

  // ---- stats reduction: 16 lanes per row (consecutive lanes in wave) ----
#pragma unroll
  for (int o = 1; o < 16; o <<= 1) {
    s1d += __shfl_xor(s1d, o);
    cnt += __shfl_xor(cnt, o);
  }
  __syncthreads();         // all waves done reading B buffers -> safe to reuse bBuf0
  float* const invsS = (float*)bBuf0;   // 32 floats
  float* const rdegS = invsS + 32;      // 32 floats
  if (sp == 0) {
    double sq = sqrt((double)cnt);
    invsS[sm] = (cnt > 0) ? (float)(1.0 / sq) : 0.0f;
    rdegS[sm] = (float)(1.0 / (s1d + sq));
  }
  __syncthreads();

  // ---- epilogue: (acc1 + invs*acc2) * rdeg, store fp32 ----
#pragma unroll
  for (int rg = 0; rg < 2; ++rg) {
    int rb = rg * 16 + ((lane >> 4) << 2);
#pragma unroll
    for (int cg = 0; cg < 2; ++cg) {
      int col = bcol + wv * 32 + cg * 16 + (lane & 15);
#pragma unroll
      for (int r = 0; r < 4; ++r) {
        int rl = rb + r;
        out[(size_t)(brow + rl) * DDIM + col] =
            (acc1[rg][cg][r] + invsS[rl] * acc2[rg][cg][r]) * rdegS[rl];
      }
    }
  }
#undef ISSUE_A
#undef ISSUE_B
#undef XFORM
#undef MFMA_TILE
}

extern "C" void kernel_launch(void* const* d_in, const int* in_sizes, int n_in,
                              void* d_out, int out_size, void* d_ws, size_t ws_size,
                              hipStream_t stream) {
  const float* cur = (const float*)d_in[0];          // [8192, 512] fp32
  const float* incm = (const float*)d_in[1];         // [8192, 8192] fp32
  float* out = (float*)d_out;                        // [8192, 512] fp32
  unsigned char* bws = (unsigned char*)d_ws;         // 8MB B chunks

  hipLaunchKernelGGL(bprep_kernel, dim3((NROWS * DDIM / 8) / 256), dim3(256), 0, stream,
                     cur, bws);
  hipLaunchKernelGGL(gemm_kernel, dim3(2, 256), dim3(512), 0, stream, incm, bws, out);
}